// Round 20
// baseline (227.443 us; speedup 1.0000x reference)
//
#include <hip/hip_runtime.h>

namespace {

typedef float f2 __attribute__((ext_vector_type(2)));
typedef float vf4 __attribute__((ext_vector_type(4)));

__device__ __forceinline__ f2 mkf2(float a, float b) { f2 r; r.x = a; r.y = b; return r; }
// r = {s,s} * b + c  -> v_pk_fma_f32
__device__ __forceinline__ f2 pkfma(float s, f2 b, f2 c) {
  return __builtin_elementwise_fma(mkf2(s, s), b, c);
}

// cos(2*pi*n/64); sin(2*pi*n/64) = COS64[(n+48)&63]
constexpr float COS64[64] = {
  1.00000000f,  0.99518473f,  0.98078528f,  0.95694034f,
  0.92387953f,  0.88192126f,  0.83146961f,  0.77301045f,
  0.70710678f,  0.63439328f,  0.55557023f,  0.47139674f,
  0.38268343f,  0.29028468f,  0.19509032f,  0.09801714f,
  0.00000000f, -0.09801714f, -0.19509032f, -0.29028468f,
 -0.38268343f, -0.47139674f, -0.55557023f, -0.63439328f,
 -0.70710678f, -0.77301045f, -0.83146961f, -0.88192126f,
 -0.92387953f, -0.95694034f, -0.98078528f, -0.99518473f,
 -1.00000000f, -0.99518473f, -0.98078528f, -0.95694034f,
 -0.92387953f, -0.88192126f, -0.83146961f, -0.77301045f,
 -0.70710678f, -0.63439328f, -0.55557023f, -0.47139674f,
 -0.38268343f, -0.29028468f, -0.19509032f, -0.09801714f,
 -0.00000000f,  0.09801714f,  0.19509032f,  0.29028468f,
  0.38268343f,  0.47139674f,  0.55557023f,  0.63439328f,
  0.70710678f,  0.77301045f,  0.83146961f,  0.88192126f,
  0.92387953f,  0.95694034f,  0.98078528f,  0.99518473f };

constexpr int MM = 144;   // 16 ky * 9 kz
constexpr int GD = 2304;  // 16 kx * 144

// multiply (r,i) by (-i)^m, m in [0,4)
__device__ __forceinline__ void rot_mi(int m, float r_in, float i_in,
                                       float& r_out, float& i_out) {
  float r  = (m & 1) ? i_in : r_in;
  float i2 = (m & 1) ? r_in : i_in;
  r  = (m >= 2) ? -r : r;
  i2 = (m == 1 || m == 2) ? -i2 : i2;
  r_out = r; i_out = i2;
}

// ---------------------------------------------------------------------------
// K1: fused z-DFT + w-DFT, TWO slices per block (R17-verified best config).
// ---------------------------------------------------------------------------
__global__ __launch_bounds__(256) void k1_fwd(const float* __restrict__ x,
                                              float2* __restrict__ buf1) {
  __shared__ float xs[64 * 68];        // [w][68], pad 4
  __shared__ float2 As[9 * 67];        // A[kz][w], padded stride
  const int tid = threadIdx.x;
  const int slice0 = blockIdx.x * 2;
  const int w = tid >> 2, q = tid & 3;
  const int s0 = tid & 15, hi = tid >> 4;

  const float4* xp0 = (const float4*)(x + ((size_t)slice0 << 12));
  float4 a0 = xp0[tid];
  float4 a1 = xp0[tid + 256];
  float4 a2 = xp0[tid + 512];
  float4 a3 = xp0[tid + 768];
  float4 b0, b1, b2, b3;

  for (int s = 0; s < 2; ++s) {
    *(float4*)&xs[(hi +  0) * 68 + s0 * 4] = a0;
    *(float4*)&xs[(hi + 16) * 68 + s0 * 4] = a1;
    *(float4*)&xs[(hi + 32) * 68 + s0 * 4] = a2;
    *(float4*)&xs[(hi + 48) * 68 + s0 * 4] = a3;
    if (s == 0) {                      // prefetch slice 1 (hides HBM latency)
      const float4* xp1 = (const float4*)(x + ((size_t)(slice0 + 1) << 12));
      b0 = xp1[tid];
      b1 = xp1[tid + 256];
      b2 = xp1[tid + 512];
      b3 = xp1[tid + 768];
    }
    __syncthreads();

    float xv[16];
    {
      const float4 c0 = *(const float4*)&xs[w * 68 + q * 16 + 0];
      const float4 c1 = *(const float4*)&xs[w * 68 + q * 16 + 4];
      const float4 c2 = *(const float4*)&xs[w * 68 + q * 16 + 8];
      const float4 c3 = *(const float4*)&xs[w * 68 + q * 16 + 12];
      xv[0]=c0.x; xv[1]=c0.y; xv[2]=c0.z; xv[3]=c0.w;
      xv[4]=c1.x; xv[5]=c1.y; xv[6]=c1.z; xv[7]=c1.w;
      xv[8]=c2.x; xv[9]=c2.y; xv[10]=c2.z; xv[11]=c2.w;
      xv[12]=c3.x; xv[13]=c3.y; xv[14]=c3.z; xv[15]=c3.w;
    }

    f2 A[9];
#pragma unroll
    for (int kz = 0; kz < 9; ++kz) A[kz] = mkf2(0.f, 0.f);
#pragma unroll
    for (int j = 0; j < 16; ++j) {
      const float v = xv[j];
#pragma unroll
      for (int kz = 0; kz < 9; ++kz) {
        const int n = (kz * j) & 63;
        A[kz] = pkfma(v, mkf2(COS64[n], -COS64[(n + 48) & 63]), A[kz]);
      }
    }
#pragma unroll
    for (int kz = 0; kz < 9; ++kz) {
      const int m = (q * kz) & 3;
      float r, i2;
      rot_mi(m, A[kz].x, A[kz].y, r, i2);
      r  += __shfl_xor(r, 1);  r  += __shfl_xor(r, 2);
      i2 += __shfl_xor(i2, 1); i2 += __shfl_xor(i2, 2);
      if (q == 0) As[kz * 67 + w] = make_float2(r, i2);
    }
    __syncthreads();

    // w-DFT radix-4
    if (tid < MM) {
      const int ky = tid / 9, kz = tid - ky * 9;
      const float cs = COS64[ky], sn = COS64[(ky + 48) & 63];
      const int m1 = ky & 3, m2 = (2 * ky) & 3, m3 = (3 * ky) & 3;
      float px = 1.f, py = 0.f, br = 0.f, bi = 0.f;
      const float2* Ak = As + kz * 67;
#pragma unroll
      for (int b = 0; b < 16; ++b) {
        const float2 v0 = Ak[b];
        const float2 v1 = Ak[b + 16];
        const float2 v2 = Ak[b + 32];
        const float2 v3 = Ak[b + 48];
        float gr = v0.x, gi = v0.y, rr, ri;
        rot_mi(m1, v1.x, v1.y, rr, ri); gr += rr; gi += ri;
        rot_mi(m2, v2.x, v2.y, rr, ri); gr += rr; gi += ri;
        rot_mi(m3, v3.x, v3.y, rr, ri); gr += rr; gi += ri;
        br = fmaf(gr, px, fmaf(-gi, py, br));
        bi = fmaf(gr, py, fmaf( gi, px, bi));
        const float nx = fmaf(px, cs,  py * sn);
        const float ny = fmaf(py, cs, -px * sn);
        px = nx; py = ny;
      }
      buf1[(size_t)(slice0 + s) * MM + tid] = make_float2(br, bi);
    }
    if (s == 0) {
      __syncthreads();                 // protect xs/As reuse for slice 1
      a0 = b0; a1 = b1; a2 = b2; a3 = b3;
    }
  }
}

// ---------------------------------------------------------------------------
// K2: fused gates + h-DFT + gate-multiply + C1 (R16-verified, unchanged).
// ---------------------------------------------------------------------------
__global__ __launch_bounds__(256) void k2_fwd(const float2* __restrict__ buf1,
    const float* __restrict__ w1, const float* __restrict__ b1,
    const float* __restrict__ w2, const float* __restrict__ b2,
    float2* __restrict__ C1buf) {
  __shared__ float2 Bs[32 * MM];       // 36,864 B
  __shared__ float2 Dg[GD];            // 18,432 B
  __shared__ float2 rotS[64 * 16];     //  8,192 B
  __shared__ float gS[GD];             //  9,216 B (gates - 1)
  __shared__ float pooled[64];
  __shared__ float hs[16];
  const int tid = threadIdx.x, bc = blockIdx.x, b = bc >> 6;
  const int kx = tid >> 4, g = tid & 15;

  // --- gates prologue ---
  {
    const int c = tid >> 2, q = tid & 3;
    const float2* bp = buf1 + ((size_t)((b * 64 + c) * 64) + q) * MM;
    float s = 0.f;
    for (int t = 0; t < 16; ++t) s += bp[(size_t)t * 4 * MM].x;
    s += __shfl_xor(s, 1); s += __shfl_xor(s, 2);
    if (q == 0) pooled[c] = s * (1.f / 262144.f);
  }
  __syncthreads();
  if (tid < 16) {
    float acc = b1[tid];
    for (int cc = 0; cc < 64; ++cc) acc = fmaf(pooled[cc], w1[cc * 16 + tid], acc);
    hs[tid] = fmaxf(acc, 0.f);
  }
  __syncthreads();
#pragma unroll
  for (int r = 0; r < 9; ++r) {
    const int o = tid + r * 256;
    float acc = b2[o];
#pragma unroll
    for (int j = 0; j < 16; ++j) acc = fmaf(hs[j], w2[j * GD + o], acc);
    gS[o] = 1.f / (1.f + expf(-acc)) - 1.f;
  }

  // rotation table rot[h][kx] = e^{+2pi i kx h/64}
#pragma unroll
  for (int u = 0; u < 4; ++u) {
    const int e = tid * 4 + u, hh = e >> 4, kxx = e & 15;
    const int n = (kxx * hh) & 63;
    rotS[e] = make_float2(COS64[n], COS64[(n + 48) & 63]);
  }

  // --- stage 1: h-DFT ---
  float accR[9], accI[9];
#pragma unroll
  for (int j = 0; j < 9; ++j) { accR[j] = 0.f; accI[j] = 0.f; }
  float qR = 1.f, qI = 0.f;            // e^{-2pi i kx h/64}
  const float hc = COS64[kx], hsn = COS64[(kx + 48) & 63];

  const float4* src = (const float4*)(buf1 + (size_t)bc * 64 * MM);
  for (int c2 = 0; c2 < 2; ++c2) {
    float4* dst4 = (float4*)Bs;
    for (int i = tid; i < 2304; i += 256) dst4[i] = src[c2 * 2304 + i];
    __syncthreads();
    for (int hh = 0; hh < 32; ++hh) {
      const float2* row = Bs + hh * MM + g * 9;
#pragma unroll
      for (int j = 0; j < 9; ++j) {
        const float2 bv = row[j];
        accR[j] = fmaf(bv.x, qR, fmaf(-bv.y, qI, accR[j]));
        accI[j] = fmaf(bv.x, qI, fmaf( bv.y, qR, accI[j]));
      }
      const float nR = fmaf(qR, hc, qI * hsn);
      const float nI = fmaf(qI, hc, -qR * hsn);
      qR = nR; qI = nI;
    }
    __syncthreads();
  }

  // gate multiply -> Dg
  {
    const float* gp = gS + kx * MM + g * 9;
    float2* dp = Dg + kx * MM + g * 9;
#pragma unroll
    for (int j = 0; j < 9; ++j) {
      const float gg = gp[j];
      dp[j] = make_float2(accR[j] * gg, accI[j] * gg);
    }
  }
  __syncthreads();

  // --- stage 2: C1 compute ---
  {
    const int h = tid >> 2, mq = tid & 3;
    float2* dst = C1buf + ((size_t)(bc * 64 + h)) * MM + mq * 36;
    for (int jb = 0; jb < 3; ++jb) {
      float aR[12], aI[12];
#pragma unroll
      for (int j = 0; j < 12; ++j) { aR[j] = 0.f; aI[j] = 0.f; }
      for (int kxx = 0; kxx < 16; ++kxx) {
        const float2 rot = rotS[h * 16 + kxx];
        const float2* drow = Dg + kxx * MM + mq * 36 + jb * 12;
#pragma unroll
        for (int j = 0; j < 12; ++j) {
          const float2 d = drow[j];
          aR[j] = fmaf(d.x, rot.x, fmaf(-d.y, rot.y, aR[j]));
          aI[j] = fmaf(d.x, rot.y, fmaf( d.y, rot.x, aI[j]));
        }
      }
#pragma unroll
      for (int j = 0; j < 12; ++j) dst[jb * 12 + j] = make_float2(aR[j], aI[j]);
    }
  }
}

// ---------------------------------------------------------------------------
// K4b: inverse synthesis, TWO slices per block. Both C1 rows AND both x
// tiles hoisted to block start (R18's hoist, WITHOUT the (256,6) clamp that
// caused the VGPR=40 spill). Compiler free to allocate ~80 VGPR; LDS already
// caps occupancy at 6 blocks/CU so the extra registers are free. Quad-local
// lgkmcnt between phases 2/3; NT full-line stores; reverse slice order.
// ---------------------------------------------------------------------------
__global__ __launch_bounds__(256) void k4b_final(const float2* __restrict__ C1buf,
                                                 const float* __restrict__ x,
                                                 float* __restrict__ out) {
  __shared__ float2 C1s[2][MM];
  __shared__ float2 C2s[9 * 65];       // C2[kz][w], padded, pre-scaled
  __shared__ float deltaS[64 * 68];    // [w][68], pad 4
  const int tid = threadIdx.x;
  const int slA = 16383 - 2 * blockIdx.x;   // reverse order for L3 x-hits
  const int slB = slA - 1;
  const int w = tid >> 2, q = tid & 3;
  const int s0 = tid & 15, hi = tid >> 4;

  // both C1 rows + BOTH x tiles in flight from block start
  if (tid < 72) {
    ((float4*)C1s[0])[tid] = ((const float4*)(C1buf + (size_t)slA * MM))[tid];
  } else if (tid >= 128 && tid < 200) {
    ((float4*)C1s[1])[tid - 128] =
        ((const float4*)(C1buf + (size_t)slB * MM))[tid - 128];
  }
  const float4* xpA = (const float4*)(x + ((size_t)slA << 12));
  float4 xv0 = xpA[tid];
  float4 xv1 = xpA[tid + 256];
  float4 xv2 = xpA[tid + 512];
  float4 xv3 = xpA[tid + 768];
  const float4* xpB = (const float4*)(x + ((size_t)slB << 12));
  float4 yv0 = xpB[tid];
  float4 yv1 = xpB[tid + 256];
  float4 yv2 = xpB[tid + 512];
  float4 yv3 = xpB[tid + 768];
  __syncthreads();

  for (int s = 0; s < 2; ++s) {
    const int slice = (s == 0) ? slA : slB;

    // phase 2 (packed): C2[kz][w] = scale * sum_ky C1[ky*9+kz] e^{+2pi i ky w/64}
    {
      const float cs = COS64[w], sn = COS64[(w + 48) & 63];
      const int kz0 = q, kz1 = q + 4;           // q==0 also does kz=8
      f2 A0 = mkf2(0.f, 0.f), A1 = mkf2(0.f, 0.f), A2 = mkf2(0.f, 0.f);
      f2 P = mkf2(1.f, 0.f);                    // {px, py}
      for (int ky = 0; ky < 16; ++ky) {
        const f2 Pn = mkf2(-P.y, P.x);
        const float2 c0 = C1s[s][ky * 9 + kz0];
        const float2 c1 = C1s[s][ky * 9 + kz1];
        A0 = pkfma(c0.x, P, A0);  A0 = pkfma(c0.y, Pn, A0);
        A1 = pkfma(c1.x, P, A1);  A1 = pkfma(c1.y, Pn, A1);
        if (q == 0) {
          const float2 c2v = C1s[s][ky * 9 + 8];
          A2 = pkfma(c2v.x, P, A2);  A2 = pkfma(c2v.y, Pn, A2);
        }
        P = pkfma(sn, Pn, cs * P);
      }
      const float scale = 1.f / 262144.f;
      C2s[kz0 * 65 + w] = make_float2(A0.x * scale, A0.y * scale);
      C2s[kz1 * 65 + w] = make_float2(A1.x * scale, A1.y * scale);
      if (q == 0) C2s[8 * 65 + w] = make_float2(A2.x * scale, A2.y * scale);
    }
    // within-quad producer->consumer: same wave, lgkmcnt suffices (no barrier)
    asm volatile("s_waitcnt lgkmcnt(0)" ::: "memory");
    __builtin_amdgcn_sched_barrier(0);

    // phase 3 (packed): delta -> padded LDS
    {
      float cr[9], ci[9];
#pragma unroll
      for (int kz = 0; kz < 9; ++kz) {
        const float2 v = C2s[kz * 65 + w];
        const int m = (kz * q) & 3;                 // multiply by i^m
        const float a = v.x, b2_ = v.y;
        float r  = (m & 1) ? b2_ : a;
        float i2 = (m & 1) ? a : b2_;
        r  = (m == 1 || m == 2) ? -r : r;
        i2 = (m >= 2) ? -i2 : i2;
        cr[kz] = r; ci[kz] = i2;
      }
      f2 acc2[8];
#pragma unroll
      for (int p = 0; p < 8; ++p) acc2[p] = mkf2(cr[0], cr[0]);
#pragma unroll
      for (int kz = 1; kz < 9; ++kz) {
#pragma unroll
        for (int p = 0; p < 8; ++p) {
          const int n0 = (kz * (2 * p)) & 63, n1 = (kz * (2 * p + 1)) & 63;
          acc2[p] = pkfma(cr[kz],
                          mkf2(2.f * COS64[n0], 2.f * COS64[n1]), acc2[p]);
          acc2[p] = pkfma(ci[kz],
                          mkf2(-2.f * COS64[(n0 + 48) & 63],
                               -2.f * COS64[(n1 + 48) & 63]), acc2[p]);
        }
      }
      float* ds = &deltaS[w * 68 + q * 16];
#pragma unroll
      for (int p = 0; p < 8; ++p) {
        ds[2 * p]     = acc2[p].x;
        ds[2 * p + 1] = acc2[p].y;
      }
    }
    __syncthreads();

    // swap-out: wave-contiguous NONTEMPORAL stores, 1KB/inst (full lines)
    {
      const float4 r0 = *(const float4*)&deltaS[(hi +  0) * 68 + s0 * 4];
      const float4 r1 = *(const float4*)&deltaS[(hi + 16) * 68 + s0 * 4];
      const float4 r2 = *(const float4*)&deltaS[(hi + 32) * 68 + s0 * 4];
      const float4 r3 = *(const float4*)&deltaS[(hi + 48) * 68 + s0 * 4];
      vf4* op = (vf4*)(out + ((size_t)slice << 12));
      vf4 o0, o1, o2, o3;
      o0.x = xv0.x + r0.x; o0.y = xv0.y + r0.y; o0.z = xv0.z + r0.z; o0.w = xv0.w + r0.w;
      o1.x = xv1.x + r1.x; o1.y = xv1.y + r1.y; o1.z = xv1.z + r1.z; o1.w = xv1.w + r1.w;
      o2.x = xv2.x + r2.x; o2.y = xv2.y + r2.y; o2.z = xv2.z + r2.z; o2.w = xv2.w + r2.w;
      o3.x = xv3.x + r3.x; o3.y = xv3.y + r3.y; o3.z = xv3.z + r3.z; o3.w = xv3.w + r3.w;
      __builtin_nontemporal_store(o0, &op[tid]);
      __builtin_nontemporal_store(o1, &op[tid + 256]);
      __builtin_nontemporal_store(o2, &op[tid + 512]);
      __builtin_nontemporal_store(o3, &op[tid + 768]);
    }
    if (s == 0) {
      xv0 = yv0; xv1 = yv1; xv2 = yv2; xv3 = yv3;
      __syncthreads();               // protect C2s/deltaS reuse
    }
  }
}

} // namespace

extern "C" void kernel_launch(void* const* d_in, const int* in_sizes, int n_in,
                              void* d_out, int out_size, void* d_ws, size_t ws_size,
                              hipStream_t stream) {
  (void)in_sizes; (void)n_in; (void)out_size; (void)ws_size;
  const float* x  = (const float*)d_in[0];
  const float* w1 = (const float*)d_in[1];
  const float* b1 = (const float*)d_in[2];
  const float* w2 = (const float*)d_in[3];
  const float* b2 = (const float*)d_in[4];
  float* out = (float*)d_out;

  char* ws = (char*)d_ws;
  float2* buf1  = (float2*)ws;                         // 16384*144*8 = 18,874,368 B
  float2* c1buf = (float2*)(ws + 18874368);            // 16384*144*8 = 18,874,368 B

  hipLaunchKernelGGL(k1_fwd,   dim3(8192),     dim3(256), 0, stream, x, buf1);
  hipLaunchKernelGGL(k2_fwd,   dim3(256),      dim3(256), 0, stream, buf1, w1, b1, w2, b2, c1buf);
  hipLaunchKernelGGL(k4b_final,dim3(8192),     dim3(256), 0, stream, c1buf, x, out);
}

// Round 21
// 208.243 us; speedup vs baseline: 1.0922x; 1.0922x over previous
//
#include <hip/hip_runtime.h>

namespace {

typedef float f2 __attribute__((ext_vector_type(2)));
typedef float vf4 __attribute__((ext_vector_type(4)));

__device__ __forceinline__ f2 mkf2(float a, float b) { f2 r; r.x = a; r.y = b; return r; }
// r = {s,s} * b + c  -> v_pk_fma_f32
__device__ __forceinline__ f2 pkfma(float s, f2 b, f2 c) {
  return __builtin_elementwise_fma(mkf2(s, s), b, c);
}

// cos(2*pi*n/64); sin(2*pi*n/64) = COS64[(n+48)&63]
constexpr float COS64[64] = {
  1.00000000f,  0.99518473f,  0.98078528f,  0.95694034f,
  0.92387953f,  0.88192126f,  0.83146961f,  0.77301045f,
  0.70710678f,  0.63439328f,  0.55557023f,  0.47139674f,
  0.38268343f,  0.29028468f,  0.19509032f,  0.09801714f,
  0.00000000f, -0.09801714f, -0.19509032f, -0.29028468f,
 -0.38268343f, -0.47139674f, -0.55557023f, -0.63439328f,
 -0.70710678f, -0.77301045f, -0.83146961f, -0.88192126f,
 -0.92387953f, -0.95694034f, -0.98078528f, -0.99518473f,
 -1.00000000f, -0.99518473f, -0.98078528f, -0.95694034f,
 -0.92387953f, -0.88192126f, -0.83146961f, -0.77301045f,
 -0.70710678f, -0.63439328f, -0.55557023f, -0.47139674f,
 -0.38268343f, -0.29028468f, -0.19509032f, -0.09801714f,
 -0.00000000f,  0.09801714f,  0.19509032f,  0.29028468f,
  0.38268343f,  0.47139674f,  0.55557023f,  0.63439328f,
  0.70710678f,  0.77301045f,  0.83146961f,  0.88192126f,
  0.92387953f,  0.95694034f,  0.98078528f,  0.99518473f };

constexpr int MM = 144;   // 16 ky * 9 kz
constexpr int GD = 2304;  // 16 kx * 144

// multiply (r,i) by (-i)^m, m in [0,4)
__device__ __forceinline__ void rot_mi(int m, float r_in, float i_in,
                                       float& r_out, float& i_out) {
  float r  = (m & 1) ? i_in : r_in;
  float i2 = (m & 1) ? r_in : i_in;
  r  = (m >= 2) ? -r : r;
  i2 = (m == 1 || m == 2) ? -i2 : i2;
  r_out = r; i_out = i2;
}

// ---------------------------------------------------------------------------
// K1: fused z-DFT + w-DFT, TWO slices per block (R16/R17-verified best).
// ---------------------------------------------------------------------------
__global__ __launch_bounds__(256) void k1_fwd(const float* __restrict__ x,
                                              float2* __restrict__ buf1) {
  __shared__ float xs[64 * 68];        // [w][68], pad 4
  __shared__ float2 As[9 * 67];        // A[kz][w], padded stride
  const int tid = threadIdx.x;
  const int slice0 = blockIdx.x * 2;
  const int w = tid >> 2, q = tid & 3;
  const int s0 = tid & 15, hi = tid >> 4;

  const float4* xp0 = (const float4*)(x + ((size_t)slice0 << 12));
  float4 a0 = xp0[tid];
  float4 a1 = xp0[tid + 256];
  float4 a2 = xp0[tid + 512];
  float4 a3 = xp0[tid + 768];
  float4 b0, b1, b2, b3;

  for (int s = 0; s < 2; ++s) {
    *(float4*)&xs[(hi +  0) * 68 + s0 * 4] = a0;
    *(float4*)&xs[(hi + 16) * 68 + s0 * 4] = a1;
    *(float4*)&xs[(hi + 32) * 68 + s0 * 4] = a2;
    *(float4*)&xs[(hi + 48) * 68 + s0 * 4] = a3;
    if (s == 0) {                      // prefetch slice 1 (hides HBM latency)
      const float4* xp1 = (const float4*)(x + ((size_t)(slice0 + 1) << 12));
      b0 = xp1[tid];
      b1 = xp1[tid + 256];
      b2 = xp1[tid + 512];
      b3 = xp1[tid + 768];
    }
    __syncthreads();

    float xv[16];
    {
      const float4 c0 = *(const float4*)&xs[w * 68 + q * 16 + 0];
      const float4 c1 = *(const float4*)&xs[w * 68 + q * 16 + 4];
      const float4 c2 = *(const float4*)&xs[w * 68 + q * 16 + 8];
      const float4 c3 = *(const float4*)&xs[w * 68 + q * 16 + 12];
      xv[0]=c0.x; xv[1]=c0.y; xv[2]=c0.z; xv[3]=c0.w;
      xv[4]=c1.x; xv[5]=c1.y; xv[6]=c1.z; xv[7]=c1.w;
      xv[8]=c2.x; xv[9]=c2.y; xv[10]=c2.z; xv[11]=c2.w;
      xv[12]=c3.x; xv[13]=c3.y; xv[14]=c3.z; xv[15]=c3.w;
    }

    f2 A[9];
#pragma unroll
    for (int kz = 0; kz < 9; ++kz) A[kz] = mkf2(0.f, 0.f);
#pragma unroll
    for (int j = 0; j < 16; ++j) {
      const float v = xv[j];
#pragma unroll
      for (int kz = 0; kz < 9; ++kz) {
        const int n = (kz * j) & 63;
        A[kz] = pkfma(v, mkf2(COS64[n], -COS64[(n + 48) & 63]), A[kz]);
      }
    }
#pragma unroll
    for (int kz = 0; kz < 9; ++kz) {
      const int m = (q * kz) & 3;
      float r, i2;
      rot_mi(m, A[kz].x, A[kz].y, r, i2);
      r  += __shfl_xor(r, 1);  r  += __shfl_xor(r, 2);
      i2 += __shfl_xor(i2, 1); i2 += __shfl_xor(i2, 2);
      if (q == 0) As[kz * 67 + w] = make_float2(r, i2);
    }
    __syncthreads();

    // w-DFT radix-4
    if (tid < MM) {
      const int ky = tid / 9, kz = tid - ky * 9;
      const float cs = COS64[ky], sn = COS64[(ky + 48) & 63];
      const int m1 = ky & 3, m2 = (2 * ky) & 3, m3 = (3 * ky) & 3;
      float px = 1.f, py = 0.f, br = 0.f, bi = 0.f;
      const float2* Ak = As + kz * 67;
#pragma unroll
      for (int b = 0; b < 16; ++b) {
        const float2 v0 = Ak[b];
        const float2 v1 = Ak[b + 16];
        const float2 v2 = Ak[b + 32];
        const float2 v3 = Ak[b + 48];
        float gr = v0.x, gi = v0.y, rr, ri;
        rot_mi(m1, v1.x, v1.y, rr, ri); gr += rr; gi += ri;
        rot_mi(m2, v2.x, v2.y, rr, ri); gr += rr; gi += ri;
        rot_mi(m3, v3.x, v3.y, rr, ri); gr += rr; gi += ri;
        br = fmaf(gr, px, fmaf(-gi, py, br));
        bi = fmaf(gr, py, fmaf( gi, px, bi));
        const float nx = fmaf(px, cs,  py * sn);
        const float ny = fmaf(py, cs, -px * sn);
        px = nx; py = ny;
      }
      buf1[(size_t)(slice0 + s) * MM + tid] = make_float2(br, bi);
    }
    if (s == 0) {
      __syncthreads();                 // protect xs/As reuse for slice 1
      a0 = b0; a1 = b1; a2 = b2; a3 = b3;
    }
  }
}

// ---------------------------------------------------------------------------
// K2: fused gates + h-DFT + gate-multiply + C1 (R16-verified, unchanged).
// ---------------------------------------------------------------------------
__global__ __launch_bounds__(256) void k2_fwd(const float2* __restrict__ buf1,
    const float* __restrict__ w1, const float* __restrict__ b1,
    const float* __restrict__ w2, const float* __restrict__ b2,
    float2* __restrict__ C1buf) {
  __shared__ float2 Bs[32 * MM];       // 36,864 B
  __shared__ float2 Dg[GD];            // 18,432 B
  __shared__ float2 rotS[64 * 16];     //  8,192 B
  __shared__ float gS[GD];             //  9,216 B (gates - 1)
  __shared__ float pooled[64];
  __shared__ float hs[16];
  const int tid = threadIdx.x, bc = blockIdx.x, b = bc >> 6;
  const int kx = tid >> 4, g = tid & 15;

  // --- gates prologue ---
  {
    const int c = tid >> 2, q = tid & 3;
    const float2* bp = buf1 + ((size_t)((b * 64 + c) * 64) + q) * MM;
    float s = 0.f;
    for (int t = 0; t < 16; ++t) s += bp[(size_t)t * 4 * MM].x;
    s += __shfl_xor(s, 1); s += __shfl_xor(s, 2);
    if (q == 0) pooled[c] = s * (1.f / 262144.f);
  }
  __syncthreads();
  if (tid < 16) {
    float acc = b1[tid];
    for (int cc = 0; cc < 64; ++cc) acc = fmaf(pooled[cc], w1[cc * 16 + tid], acc);
    hs[tid] = fmaxf(acc, 0.f);
  }
  __syncthreads();
#pragma unroll
  for (int r = 0; r < 9; ++r) {
    const int o = tid + r * 256;
    float acc = b2[o];
#pragma unroll
    for (int j = 0; j < 16; ++j) acc = fmaf(hs[j], w2[j * GD + o], acc);
    gS[o] = 1.f / (1.f + expf(-acc)) - 1.f;
  }

  // rotation table rot[h][kx] = e^{+2pi i kx h/64}
#pragma unroll
  for (int u = 0; u < 4; ++u) {
    const int e = tid * 4 + u, hh = e >> 4, kxx = e & 15;
    const int n = (kxx * hh) & 63;
    rotS[e] = make_float2(COS64[n], COS64[(n + 48) & 63]);
  }

  // --- stage 1: h-DFT ---
  float accR[9], accI[9];
#pragma unroll
  for (int j = 0; j < 9; ++j) { accR[j] = 0.f; accI[j] = 0.f; }
  float qR = 1.f, qI = 0.f;            // e^{-2pi i kx h/64}
  const float hc = COS64[kx], hsn = COS64[(kx + 48) & 63];

  const float4* src = (const float4*)(buf1 + (size_t)bc * 64 * MM);
  for (int c2 = 0; c2 < 2; ++c2) {
    float4* dst4 = (float4*)Bs;
    for (int i = tid; i < 2304; i += 256) dst4[i] = src[c2 * 2304 + i];
    __syncthreads();
    for (int hh = 0; hh < 32; ++hh) {
      const float2* row = Bs + hh * MM + g * 9;
#pragma unroll
      for (int j = 0; j < 9; ++j) {
        const float2 bv = row[j];
        accR[j] = fmaf(bv.x, qR, fmaf(-bv.y, qI, accR[j]));
        accI[j] = fmaf(bv.x, qI, fmaf( bv.y, qR, accI[j]));
      }
      const float nR = fmaf(qR, hc, qI * hsn);
      const float nI = fmaf(qI, hc, -qR * hsn);
      qR = nR; qI = nI;
    }
    __syncthreads();
  }

  // gate multiply -> Dg
  {
    const float* gp = gS + kx * MM + g * 9;
    float2* dp = Dg + kx * MM + g * 9;
#pragma unroll
    for (int j = 0; j < 9; ++j) {
      const float gg = gp[j];
      dp[j] = make_float2(accR[j] * gg, accI[j] * gg);
    }
  }
  __syncthreads();

  // --- stage 2: C1 compute ---
  {
    const int h = tid >> 2, mq = tid & 3;
    float2* dst = C1buf + ((size_t)(bc * 64 + h)) * MM + mq * 36;
    for (int jb = 0; jb < 3; ++jb) {
      float aR[12], aI[12];
#pragma unroll
      for (int j = 0; j < 12; ++j) { aR[j] = 0.f; aI[j] = 0.f; }
      for (int kxx = 0; kxx < 16; ++kxx) {
        const float2 rot = rotS[h * 16 + kxx];
        const float2* drow = Dg + kxx * MM + mq * 36 + jb * 12;
#pragma unroll
        for (int j = 0; j < 12; ++j) {
          const float2 d = drow[j];
          aR[j] = fmaf(d.x, rot.x, fmaf(-d.y, rot.y, aR[j]));
          aI[j] = fmaf(d.x, rot.y, fmaf( d.y, rot.x, aI[j]));
        }
      }
#pragma unroll
      for (int j = 0; j < 12; ++j) dst[jb * 12 + j] = make_float2(aR[j], aI[j]);
    }
  }
}

// ---------------------------------------------------------------------------
// K4b: inverse synthesis, TWO slices per block with C1 double-buffer
// (R17-verified best). Slice B's x loads issue after slice A's stores,
// hiding under B's compute. Quad-local lgkmcnt between phases 2/3; NT
// full-line stores; reverse slice order. No min-waves clamp (R18 lesson).
// ---------------------------------------------------------------------------
__global__ __launch_bounds__(256) void k4b_final(const float2* __restrict__ C1buf,
                                                 const float* __restrict__ x,
                                                 float* __restrict__ out) {
  __shared__ float2 C1s[2][MM];
  __shared__ float2 C2s[9 * 65];       // C2[kz][w], padded, pre-scaled
  __shared__ float deltaS[64 * 68];    // [w][68], pad 4
  const int tid = threadIdx.x;
  const int slA = 16383 - 2 * blockIdx.x;   // reverse order for L3 x-hits
  const int slB = slA - 1;
  const int w = tid >> 2, q = tid & 3;
  const int s0 = tid & 15, hi = tid >> 4;

  // both C1 rows load at block start (slice B's stall eliminated)
  if (tid < 72) {
    ((float4*)C1s[0])[tid] = ((const float4*)(C1buf + (size_t)slA * MM))[tid];
  } else if (tid >= 128 && tid < 200) {
    ((float4*)C1s[1])[tid - 128] =
        ((const float4*)(C1buf + (size_t)slB * MM))[tid - 128];
  }
  // x for slice A (wave-contiguous, 1KB/inst)
  const float4* xpA = (const float4*)(x + ((size_t)slA << 12));
  float4 xv0 = xpA[tid];
  float4 xv1 = xpA[tid + 256];
  float4 xv2 = xpA[tid + 512];
  float4 xv3 = xpA[tid + 768];
  __syncthreads();

  for (int s = 0; s < 2; ++s) {
    const int slice = (s == 0) ? slA : slB;

    // phase 2 (packed): C2[kz][w] = scale * sum_ky C1[ky*9+kz] e^{+2pi i ky w/64}
    {
      const float cs = COS64[w], sn = COS64[(w + 48) & 63];
      const int kz0 = q, kz1 = q + 4;           // q==0 also does kz=8
      f2 A0 = mkf2(0.f, 0.f), A1 = mkf2(0.f, 0.f), A2 = mkf2(0.f, 0.f);
      f2 P = mkf2(1.f, 0.f);                    // {px, py}
      for (int ky = 0; ky < 16; ++ky) {
        const f2 Pn = mkf2(-P.y, P.x);
        const float2 c0 = C1s[s][ky * 9 + kz0];
        const float2 c1 = C1s[s][ky * 9 + kz1];
        A0 = pkfma(c0.x, P, A0);  A0 = pkfma(c0.y, Pn, A0);
        A1 = pkfma(c1.x, P, A1);  A1 = pkfma(c1.y, Pn, A1);
        if (q == 0) {
          const float2 c2v = C1s[s][ky * 9 + 8];
          A2 = pkfma(c2v.x, P, A2);  A2 = pkfma(c2v.y, Pn, A2);
        }
        P = pkfma(sn, Pn, cs * P);
      }
      const float scale = 1.f / 262144.f;
      C2s[kz0 * 65 + w] = make_float2(A0.x * scale, A0.y * scale);
      C2s[kz1 * 65 + w] = make_float2(A1.x * scale, A1.y * scale);
      if (q == 0) C2s[8 * 65 + w] = make_float2(A2.x * scale, A2.y * scale);
    }
    // within-quad producer->consumer: same wave, lgkmcnt suffices (no barrier)
    asm volatile("s_waitcnt lgkmcnt(0)" ::: "memory");
    __builtin_amdgcn_sched_barrier(0);

    // phase 3 (packed): delta -> padded LDS
    {
      float cr[9], ci[9];
#pragma unroll
      for (int kz = 0; kz < 9; ++kz) {
        const float2 v = C2s[kz * 65 + w];
        const int m = (kz * q) & 3;                 // multiply by i^m
        const float a = v.x, b2_ = v.y;
        float r  = (m & 1) ? b2_ : a;
        float i2 = (m & 1) ? a : b2_;
        r  = (m == 1 || m == 2) ? -r : r;
        i2 = (m >= 2) ? -i2 : i2;
        cr[kz] = r; ci[kz] = i2;
      }
      f2 acc2[8];
#pragma unroll
      for (int p = 0; p < 8; ++p) acc2[p] = mkf2(cr[0], cr[0]);
#pragma unroll
      for (int kz = 1; kz < 9; ++kz) {
#pragma unroll
        for (int p = 0; p < 8; ++p) {
          const int n0 = (kz * (2 * p)) & 63, n1 = (kz * (2 * p + 1)) & 63;
          acc2[p] = pkfma(cr[kz],
                          mkf2(2.f * COS64[n0], 2.f * COS64[n1]), acc2[p]);
          acc2[p] = pkfma(ci[kz],
                          mkf2(-2.f * COS64[(n0 + 48) & 63],
                               -2.f * COS64[(n1 + 48) & 63]), acc2[p]);
        }
      }
      float* ds = &deltaS[w * 68 + q * 16];
#pragma unroll
      for (int p = 0; p < 8; ++p) {
        ds[2 * p]     = acc2[p].x;
        ds[2 * p + 1] = acc2[p].y;
      }
    }
    __syncthreads();

    // swap-out: wave-contiguous NONTEMPORAL stores, 1KB/inst (full lines)
    {
      const float4 r0 = *(const float4*)&deltaS[(hi +  0) * 68 + s0 * 4];
      const float4 r1 = *(const float4*)&deltaS[(hi + 16) * 68 + s0 * 4];
      const float4 r2 = *(const float4*)&deltaS[(hi + 32) * 68 + s0 * 4];
      const float4 r3 = *(const float4*)&deltaS[(hi + 48) * 68 + s0 * 4];
      vf4* op = (vf4*)(out + ((size_t)slice << 12));
      vf4 o0, o1, o2, o3;
      o0.x = xv0.x + r0.x; o0.y = xv0.y + r0.y; o0.z = xv0.z + r0.z; o0.w = xv0.w + r0.w;
      o1.x = xv1.x + r1.x; o1.y = xv1.y + r1.y; o1.z = xv1.z + r1.z; o1.w = xv1.w + r1.w;
      o2.x = xv2.x + r2.x; o2.y = xv2.y + r2.y; o2.z = xv2.z + r2.z; o2.w = xv2.w + r2.w;
      o3.x = xv3.x + r3.x; o3.y = xv3.y + r3.y; o3.z = xv3.z + r3.z; o3.w = xv3.w + r3.w;
      __builtin_nontemporal_store(o0, &op[tid]);
      __builtin_nontemporal_store(o1, &op[tid + 256]);
      __builtin_nontemporal_store(o2, &op[tid + 512]);
      __builtin_nontemporal_store(o3, &op[tid + 768]);
    }
    if (s == 0) {
      // x for slice B; latency hides under slice B's phases 2-3
      const float4* xpB = (const float4*)(x + ((size_t)slB << 12));
      xv0 = xpB[tid];
      xv1 = xpB[tid + 256];
      xv2 = xpB[tid + 512];
      xv3 = xpB[tid + 768];
      __syncthreads();               // protect C2s/deltaS reuse
    }
  }
}

} // namespace

extern "C" void kernel_launch(void* const* d_in, const int* in_sizes, int n_in,
                              void* d_out, int out_size, void* d_ws, size_t ws_size,
                              hipStream_t stream) {
  (void)in_sizes; (void)n_in; (void)out_size; (void)ws_size;
  const float* x  = (const float*)d_in[0];
  const float* w1 = (const float*)d_in[1];
  const float* b1 = (const float*)d_in[2];
  const float* w2 = (const float*)d_in[3];
  const float* b2 = (const float*)d_in[4];
  float* out = (float*)d_out;

  char* ws = (char*)d_ws;
  float2* buf1  = (float2*)ws;                         // 16384*144*8 = 18,874,368 B
  float2* c1buf = (float2*)(ws + 18874368);            // 16384*144*8 = 18,874,368 B

  hipLaunchKernelGGL(k1_fwd,   dim3(8192),     dim3(256), 0, stream, x, buf1);
  hipLaunchKernelGGL(k2_fwd,   dim3(256),      dim3(256), 0, stream, buf1, w1, b1, w2, b2, c1buf);
  hipLaunchKernelGGL(k4b_final,dim3(8192),     dim3(256), 0, stream, c1buf, x, out);
}